// Round 18
// baseline (503.298 us; speedup 1.0000x reference)
//
#include <hip/hip_runtime.h>

#define DEPTH 4
#define CDIM 512
#define TDIM 1024
#define BDIM 8
#define HDIM 8
#define DHEAD 64
#define FFDIM 2048
#define MROWS (BDIM*TDIM)  // 8192 rows

// softmax scale folded into Wq/bq: 0.125 * log2(e)
#define QK_SCALE_LOG2E 0.18033688f

typedef __attribute__((ext_vector_type(8))) short bf16x8;
typedef __attribute__((ext_vector_type(4))) short s16x4;
typedef __attribute__((ext_vector_type(4))) float f32x4;

__device__ __forceinline__ f32x4 mfma16(bf16x8 a, bf16x8 b, f32x4 c) {
  return __builtin_amdgcn_mfma_f32_16x16x32_bf16(a, b, c, 0, 0, 0);
}

__device__ __forceinline__ unsigned short f2bf(float f) {
  union { float f; unsigned u; } v; v.f = f;
  unsigned r = v.u + 0x7fffu + ((v.u >> 16) & 1u);
  return (unsigned short)(r >> 16);
}

__device__ __forceinline__ float bf2f(unsigned short u) {
  return __uint_as_float((unsigned)u << 16);
}

__device__ __forceinline__ void gload_lds16(const void* g, void* l) {
  __builtin_amdgcn_global_load_lds(
      (const __attribute__((address_space(1))) unsigned int*)g,
      (__attribute__((address_space(3))) unsigned int*)l, 16, 0, 0);
}

__device__ __forceinline__ unsigned lds_addr(const void* p) {
  return (unsigned)(unsigned long long)p;
}

// gelu(x) = x * sigmoid(1.5957691*(x+0.044715x^3)); exp2 form folds log2e
// into the constant: 1.5957691*log2e = 2.3022082. Overflow-safe both ends.
__device__ __forceinline__ float gelu_f(float x) {
  float u = 2.3022082f * (x + 0.044715f * x * x * x);
  return x * __builtin_amdgcn_rcpf(1.0f + __builtin_amdgcn_exp2f(-u));
}

// ---------------- weight transpose + cast: W[K][N] f32 -> Wt[N][K] bf16 ----
// Output rows n < scale_rows are multiplied by scale (Q-column softmax fold).
__global__ __launch_bounds__(256)
void transpose_cast(const float* __restrict__ W, unsigned short* __restrict__ Wt,
                    int K, int N, int scale_rows, float scale) {
  __shared__ float t[32][33];
  const int zl = blockIdx.z;
  W  += (size_t)zl * K * N;
  Wt += (size_t)zl * K * N;
  int n0 = blockIdx.x * 32, k0 = blockIdx.y * 32;
  int tx = threadIdx.x & 31, ty = threadIdx.x >> 5;  // 32 x 8
  for (int i = 0; i < 32; i += 8)
    t[ty + i][tx] = W[(size_t)(k0 + ty + i) * N + n0 + tx];
  __syncthreads();
  for (int i = 0; i < 32; i += 8) {
    float v = t[tx][ty + i];
    if (n0 + ty + i < scale_rows) v *= scale;
    Wt[(size_t)(n0 + ty + i) * K + k0 + tx] = f2bf(v);
  }
}

// ---------------- LayerNorm: x (f32 or bf16) [8192][512] -> h bf16 ---------
template<int BF>
__global__ __launch_bounds__(256)
void ln_kernel(const void* __restrict__ xv, const float* __restrict__ g,
               const float* __restrict__ bta, unsigned short* __restrict__ h) {
  int row  = blockIdx.x * 4 + (threadIdx.x >> 6);
  int lane = threadIdx.x & 63;
  float vv[8];
  if (BF) {
    const unsigned short* xr = (const unsigned short*)xv + (size_t)row * CDIM;
    bf16x8 b0 = *(const bf16x8*)(xr + lane * 8);
    for (int j = 0; j < 8; ++j) vv[j] = bf2f(((const unsigned short*)&b0)[j]);
  } else {
    const float* xr = (const float*)xv + (size_t)row * CDIM;
    float4 v0 = ((const float4*)xr)[lane * 2];
    float4 v1 = ((const float4*)xr)[lane * 2 + 1];
    vv[0] = v0.x; vv[1] = v0.y; vv[2] = v0.z; vv[3] = v0.w;
    vv[4] = v1.x; vv[5] = v1.y; vv[6] = v1.z; vv[7] = v1.w;
  }
  float s = 0.f, sq = 0.f;
  for (int j = 0; j < 8; ++j) { s += vv[j]; sq += vv[j] * vv[j]; }
  for (int m = 1; m < 64; m <<= 1) { s += __shfl_xor(s, m); sq += __shfl_xor(sq, m); }
  float mu  = s * (1.0f / CDIM);
  float var = sq * (1.0f / CDIM) - mu * mu;
  float rs  = rsqrtf(var + 1e-5f);
  int c0 = lane * 8;
  bf16x8 hv;
  for (int j = 0; j < 8; ++j)
    ((short*)&hv)[j] = (short)f2bf((vv[j] - mu) * rs * g[c0 + j] + bta[c0 + j]);
  *(bf16x8*)(h + (size_t)row * CDIM + c0) = hv;
}

// ---------------- GEMM: C[M,N] = A[M,K](bf16) @ Bt[N,K]^T(bf16) + epilogue -
// EPI 0: +bias -> bf16 (trunc).  EPI 1: gelu(+bias) -> bf16 (trunc).
// EPI 2: +bias+resid; RBF: resid is bf16; OBF: output bf16 (f2bf) else f32.
// QSC: scale bias for cols<CDIM (Q-column weight fold).
// BK=64, 8-slot XOR swizzle via pre-swizzled global source.
// DEPTH-2 prefetch on 3 buffers, single barrier/K-step:
//   per iter: vmcnt(LVM) [my ks loads landed] -> barrier [all waves' loads
//   landed + all ks-1 reads done] -> stage(ks+2) into buf (ks-1)%3 [safe] ->
//   reads+MFMA. Each stage gets TWO loop bodies of latency slack.
// BM=256,BN=128 (QKV/FFN1): 512 thr, 8 waves 4x2, 144KB LDS, 1 block/CU.
// BM=128,BN=64 (proj/FFN2): 256 thr, 4 waves, 72KB LDS, 2 blocks/CU.
template<int N, int K, int EPI, int BM, int BN, int QSC = 0, int RBF = 0, int OBF = 0>
__global__ __launch_bounds__((BM == 256) ? 512 : 256, 2)
void gemm_bt(const unsigned short* __restrict__ A,
             const unsigned short* __restrict__ Bt,
             const float* __restrict__ bias,
             const void* __restrict__ resid,
             void* __restrict__ outp) {
  constexpr int THREADS = (BM == 256) ? 512 : 256;
  constexpr int NWAVE   = THREADS / 64;
  constexpr int WCN     = BN / 64;            // wave columns (2 or 1)
  constexpr int WRN     = NWAVE / WCN;        // wave rows (4)
  constexpr int MI      = BM / WRN / 16;      // acc row-frags per wave (4 or 2)
  constexpr int NK      = K / 64;
  constexpr int LVM     = (BM + BN) * 8 / THREADS;  // = 6 for both variants
  constexpr int NBUF    = 3;
  __shared__ unsigned short As[NBUF][BM * 64];
  __shared__ unsigned short Bs[NBUF][BN * 64];
  const int tid  = threadIdx.x;
  const int wave = tid >> 6, lane = tid & 63;
  const int l16  = lane & 15, lq = lane >> 4;
  const int tm = blockIdx.x, tn = blockIdx.y;
  const int wr = wave / WCN, wc = wave % WCN;

  auto stage = [&](int ks, int bb) {
    for (int it = 0; it < BM * 8 / THREADS; ++it) {   // A: BM rows x 128B
      int idx = it * THREADS + tid;
      int row = idx >> 3;
      int co  = ((idx & 7) ^ (row & 7)) * 8;  // pre-swizzled source slot
      gload_lds16(A + (size_t)(tm * BM + row) * K + ks * 64 + co,
                  &As[bb][(it * THREADS + wave * 64) * 8]);
    }
    for (int it = 0; it < BN * 8 / THREADS; ++it) {   // B: BN rows x 128B
      int idx = it * THREADS + tid;
      int row = idx >> 3;
      int co  = ((idx & 7) ^ (row & 7)) * 8;
      gload_lds16(Bt + (size_t)(tn * BN + row) * K + ks * 64 + co,
                  &Bs[bb][(it * THREADS + wave * 64) * 8]);
    }
  };

  f32x4 acc[MI][4] = {};
  stage(0, 0);
  stage(1, 1);                                       // depth-2 prologue
  int cur = 0;
  for (int ks = 0; ks < NK; ++ks) {
    if (ks + 1 < NK) {
      asm volatile("s_waitcnt vmcnt(%c0)" :: "i"(LVM) : "memory");  // ks landed
    } else {
      asm volatile("s_waitcnt vmcnt(0)" ::: "memory");
    }
    asm volatile("s_barrier" ::: "memory");          // the ONLY barrier per step
    if (ks + 2 < NK) {
      int nb = cur + 2; if (nb >= NBUF) nb -= NBUF;
      stage(ks + 2, nb);                             // depth-2 prefetch
    }
    bf16x8 af[MI][2], bfr[4][2];
    const char* aBase = (const char*)&As[cur][0];
    const char* bBase = (const char*)&Bs[cur][0];
    const int swz = (l16 & 7);
    #pragma unroll
    for (int i = 0; i < MI; ++i) {
      int row = wr * (MI * 16) + i * 16 + l16;
      #pragma unroll
      for (int t = 0; t < 2; ++t)
        af[i][t] = *(const bf16x8*)(aBase + row * 128 + (((t * 4 + lq) ^ swz) * 16));
    }
    #pragma unroll
    for (int j = 0; j < 4; ++j) {
      int row = wc * 64 + j * 16 + l16;
      #pragma unroll
      for (int t = 0; t < 2; ++t)
        bfr[j][t] = *(const bf16x8*)(bBase + row * 128 + (((t * 4 + lq) ^ swz) * 16));
    }
    __builtin_amdgcn_s_setprio(1);
    #pragma unroll
    for (int t = 0; t < 2; ++t)
      #pragma unroll
      for (int i = 0; i < MI; ++i)
        #pragma unroll
        for (int j = 0; j < 4; ++j)
          acc[i][j] = mfma16(af[i][t], bfr[j][t], acc[i][j]);
    __builtin_amdgcn_s_setprio(0);
    ++cur; if (cur == NBUF) cur = 0;                 // no trailing barrier
  }
  const int rowbase = tm * BM + wr * (MI * 16);
  const int colbase = tn * BN + wc * 64;
  for (int j = 0; j < 4; ++j) {
    int col = colbase + j * 16 + l16;
    float bv = bias[col];
    if (QSC && col < CDIM) bv *= QK_SCALE_LOG2E;   // Q-column bias fold
    for (int i = 0; i < MI; ++i) {
      for (int r = 0; r < 4; ++r) {
        int row = rowbase + i * 16 + lq * 4 + r;
        float v = acc[i][j][r] + bv;
        if (EPI == 1) v = gelu_f(v);
        if (EPI == 2) {
          size_t off = (size_t)row * N + col;
          float rv = RBF ? bf2f(((const unsigned short*)resid)[off])
                         : ((const float*)resid)[off];
          float sv = v + rv;
          if (OBF) ((unsigned short*)outp)[off] = f2bf(sv);  // RNE: x-walk safe
          else     ((float*)outp)[off] = sv;
        } else {
          // bf16 truncation store -> global_store_short_d16_hi (no round ops)
          ((unsigned short*)outp)[(size_t)row * N + col] =
              (unsigned short)(__float_as_uint(v) >> 16);
        }
      }
    }
  }
}

// ---------------- flash attention: qkv bf16 [8192][1536] -> o bf16 [8192][512]
// (round-16 proven config) QBLK=128, 4 waves. Q-columns pre-scaled by
// 0.125*log2e -> p = exp2(s). K staged to LDS (byte-swizzled), V tr-subtiled
// with 528-elem chunk stride (conflict-free tr-reads). d16_hi P-store.
// 3-buffer K/V rotation -> single barrier/tile. blockIdx&7 = batch (XCD-pin).
__global__ __launch_bounds__(256, 2)
void attn_kernel(const unsigned short* __restrict__ qkv,
                 unsigned short* __restrict__ o) {
  __shared__ unsigned short Ks[3][64 * 64];
  __shared__ unsigned short Vs[3][8 * 528];   // 8 chunks x 528 (16 pad elems)
  __shared__ unsigned short Ps[128 * 72];
  const int tid  = threadIdx.x;
  const int wave = tid >> 6, lane = tid & 63;
  const int l16  = lane & 15, lq = lane >> 4;
  const int bid  = blockIdx.x;
  const int b    = bid & 7;                   // XCD-pinned batch
  const int h    = (bid >> 3) & 7;
  const int qt   = bid >> 6;                  // 0..7 (128-row q tiles)
  const size_t rowbase = (size_t)b * TDIM;
  const int swzA = (l16 & 7) << 4;

  // ---- Q in registers: A-frag rows = qt*128 + mi*64 + wave*16 + l16 ----
  bf16x8 aq[2][2];
  #pragma unroll
  for (int mi = 0; mi < 2; ++mi) {
    const unsigned short* qr =
        qkv + (rowbase + qt * 128 + mi * 64 + wave * 16 + l16) * (3 * CDIM) + h * DHEAD;
    aq[mi][0] = *(const bf16x8*)(qr + lq * 8);
    aq[mi][1] = *(const bf16x8*)(qr + 32 + lq * 8);
  }

  auto stageKV = [&](int kvt, int bb) {
    for (int it = 0; it < 2; ++it) {
      int i  = it * 256 + tid;
      int r  = i >> 3;
      int cb = ((i & 7) << 4) ^ ((r & 7) << 4);
      gload_lds16(qkv + (rowbase + kvt * 64 + r) * (3 * CDIM) + CDIM + h * DHEAD + (cb >> 1),
                  &Ks[bb][(it * 256 + wave * 64) * 8]);
      int c  = it * 4 + wave;                       // chunk 0..7 (512 elems)
      int k2 = (c * 2 + (lane >> 5)) * 4 + ((lane >> 1) & 3);
      int d0 = ((lane >> 3) & 3) * 16 + (lane & 1) * 8;
      gload_lds16(qkv + (rowbase + kvt * 64 + k2) * (3 * CDIM) + 2 * CDIM + h * DHEAD + d0,
                  &Vs[bb][c * 528]);                // padded chunk stride
    }
  };

  stageKV(0, 0);                                    // 4 loads in flight

  f32x4 ofr[2][4] = {};
  float lsum[2][4] = {};
  const unsigned psbase =
      lds_addr(Ps) + ((unsigned)(wave * 16 + lq * 4) * 72 + l16) * 2;

  int cur = 0;
  for (int kv = 0; kv < TDIM / 64; ++kv) {
    if (kv < TDIM / 64 - 1) {
      int nb = cur + 1; if (nb == 3) nb = 0;
      stageKV(kv + 1, nb);                          // prefetch next tile
      asm volatile("s_waitcnt vmcnt(4)" ::: "memory");  // cur tile landed
    } else {
      asm volatile("s_waitcnt vmcnt(0)" ::: "memory");
    }
    asm volatile("s_barrier" ::: "memory");         // the ONLY barrier per tile

    // ---- S = Q K^T (Q pre-scaled by 0.125*log2e) ----
    f32x4 s[2][4] = {};
    __builtin_amdgcn_s_setprio(1);
    #pragma unroll
    for (int kk = 0; kk < 2; ++kk) {
      bf16x8 bk[4];
      #pragma unroll
      for (int n = 0; n < 4; ++n)
        bk[n] = *(const bf16x8*)((const char*)&Ks[cur][0] +
                  (((n * 16 + l16) * 128 + (kk * 32 + lq * 8) * 2) ^ swzA));
      #pragma unroll
      for (int mi = 0; mi < 2; ++mi)
        #pragma unroll
        for (int n = 0; n < 4; ++n)
          s[mi][n] = mfma16(aq[mi][kk], bk[n], s[mi][n]);
    }
    __builtin_amdgcn_s_setprio(0);

    // ---- issue 16 V tr-reads; exp VALU hides their latency ----
    s16x4 tr[8][2];
    {
      unsigned va = lds_addr(&Vs[cur][0]) + lq * 1056 + l16 * 8;
      #pragma unroll
      for (int kk = 0; kk < 2; ++kk)
        #pragma unroll
        for (int n = 0; n < 4; ++n) {
          asm volatile("ds_read_b64_tr_b16 %0, %1 offset:%c2"
                       : "=v"(tr[kk * 4 + n][0]) : "v"(va), "i"(kk * 4224 + n * 128));
          asm volatile("ds_read_b64_tr_b16 %0, %1 offset:%c2"
                       : "=v"(tr[kk * 4 + n][1]) : "v"(va), "i"(kk * 4224 + n * 128 + 512));
        }
    }

    // ---- p = exp2(s) (scale pre-folded); d16_hi bf16 store (zero VALU) ----
    #pragma unroll
    for (int mi = 0; mi < 2; ++mi)
      #pragma unroll
      for (int n = 0; n < 4; ++n)
        #pragma unroll
        for (int r = 0; r < 4; ++r) {
          float p = __builtin_amdgcn_exp2f(s[mi][n][r]);
          lsum[mi][r] += p;
          asm volatile("ds_write_b16_d16_hi %0, %1 offset:%c2"
                       :: "v"(psbase), "v"(p),
                          "i"(mi * 9216 + r * 144 + n * 32) : "memory");
        }

    asm volatile("s_waitcnt lgkmcnt(0)" ::: "memory");
    __builtin_amdgcn_sched_barrier(0);

    // ---- O += P @ V ----
    __builtin_amdgcn_s_setprio(1);
    #pragma unroll
    for (int kk = 0; kk < 2; ++kk) {
      bf16x8 ap[2];
      #pragma unroll
      for (int mi = 0; mi < 2; ++mi)
        ap[mi] = *(const bf16x8*)&Ps[(mi * 64 + wave * 16 + l16) * 72 + kk * 32 + lq * 8];
      #pragma unroll
      for (int n = 0; n < 4; ++n) {
        bf16x8 bv = __builtin_shufflevector(tr[kk * 4 + n][0], tr[kk * 4 + n][1],
                                            0, 1, 2, 3, 4, 5, 6, 7);
        #pragma unroll
        for (int mi = 0; mi < 2; ++mi)
          ofr[mi][n] = mfma16(ap[mi], bv, ofr[mi][n]);
      }
    }
    __builtin_amdgcn_s_setprio(0);

    ++cur; if (cur == 3) cur = 0;                   // no trailing barrier
  }

  // ---- deferred denominator reduce (once) + output ----
  for (int msk = 1; msk < 16; msk <<= 1)
    #pragma unroll
    for (int mi = 0; mi < 2; ++mi)
      #pragma unroll
      for (int r = 0; r < 4; ++r) lsum[mi][r] += __shfl_xor(lsum[mi][r], msk);
  for (int mi = 0; mi < 2; ++mi)
    for (int n = 0; n < 4; ++n)
      for (int r = 0; r < 4; ++r) {
        size_t row = rowbase + qt * 128 + mi * 64 + wave * 16 + lq * 4 + r;
        o[row * CDIM + h * DHEAD + n * 16 + l16] = f2bf(ofr[mi][n][r] / lsum[mi][r]);
      }
}

// ---------------------------------------------------------------------------
extern "C" void kernel_launch(void* const* d_in, const int* in_sizes, int n_in,
                              void* d_out, int out_size, void* d_ws, size_t ws_size,
                              hipStream_t stream) {
  (void)in_sizes; (void)n_in; (void)out_size;
  const float* x_in = (const float*)d_in[0];
  const float* Wqkv = (const float*)d_in[1];
  const float* bqkv = (const float*)d_in[2];
  const float* Wo   = (const float*)d_in[3];
  const float* bo   = (const float*)d_in[4];
  const float* W1   = (const float*)d_in[5];
  const float* b1   = (const float*)d_in[6];
  const float* W2   = (const float*)d_in[7];
  const float* b2   = (const float*)d_in[8];
  const float* ln1g = (const float*)d_in[9];
  const float* ln1b = (const float*)d_in[10];
  const float* ln2g = (const float*)d_in[11];
  const float* ln2b = (const float*)d_in[12];

  float* x = (float*)d_out;  // f32 residual stream (fallback path)
  unsigned short* hbuf  = (unsigned short*)d_ws;              // 8 MB  (h / o, bf16)
  unsigned short* big   = hbuf  + (size_t)MROWS * CDIM;       // 32 MB (qkv / ff, bf16)
  unsigned short* wqkvT = big   + (size_t)MROWS * FFDIM;      // weights bf16, transposed
  unsigned short* woT   = wqkvT + (size_t)DEPTH * 3 * CDIM * CDIM;
  unsigned short* w1T   = woT   + (size_t)DEPTH * CDIM * CDIM;
  unsigned short* w2T   = w1T   + (size_t)DEPTH * FFDIM * CDIM;
  unsigned short* xb    = w2T   + (size_t)DEPTH * CDIM * FFDIM;  // bf16 x, 8 MB
  const bool useBf16X = ws_size >= (size_t)72 * 1024 * 1024;

  transpose_cast<<<dim3(3 * CDIM / 32, CDIM / 32, DEPTH), 256, 0, stream>>>(
      Wqkv, wqkvT, CDIM, 3 * CDIM, CDIM, QK_SCALE_LOG2E);  // scale Q-columns
  transpose_cast<<<dim3(CDIM / 32, CDIM / 32, DEPTH), 256, 0, stream>>>(
      Wo, woT, CDIM, CDIM, 0, 1.0f);
  transpose_cast<<<dim3(FFDIM / 32, CDIM / 32, DEPTH), 256, 0, stream>>>(
      W1, w1T, CDIM, FFDIM, 0, 1.0f);
  transpose_cast<<<dim3(CDIM / 32, FFDIM / 32, DEPTH), 256, 0, stream>>>(
      W2, w2T, FFDIM, CDIM, 0, 1.0f);

  const dim3 gQKV(MROWS / 256, 3 * CDIM / 128), gP(MROWS / 128, CDIM / 64);
  const dim3 gF1(MROWS / 256, FFDIM / 128), gLN(MROWS / 4);
  const dim3 gAT(BDIM * HDIM * TDIM / 128);

  for (int l = 0; l < DEPTH; ++l) {
    const float* bq = bqkv + l * 3 * CDIM;
    const unsigned short* wq = wqkvT + (size_t)l * 3 * CDIM * CDIM;
    const unsigned short* wo = woT + (size_t)l * CDIM * CDIM;
    const unsigned short* w1 = w1T + (size_t)l * FFDIM * CDIM;
    const unsigned short* w2 = w2T + (size_t)l * CDIM * FFDIM;
    if (useBf16X) {
      // ---- bf16 residual stream in xb; final FFN2 writes f32 d_out ----
      if (l == 0)
        ln_kernel<0><<<gLN, 256, 0, stream>>>(x_in, ln1g, ln1b, hbuf);
      else
        ln_kernel<1><<<gLN, 256, 0, stream>>>(xb, ln1g + l * CDIM, ln1b + l * CDIM, hbuf);
      gemm_bt<3 * CDIM, CDIM, 0, 256, 128, 1><<<gQKV, 512, 0, stream>>>(
          hbuf, wq, bq, nullptr, big);
      attn_kernel<<<gAT, 256, 0, stream>>>(big, hbuf);
      if (l == 0)
        gemm_bt<CDIM, CDIM, 2, 128, 64, 0, 0, 1><<<gP, 256, 0, stream>>>(
            hbuf, wo, bo + l * CDIM, x_in, xb);
      else
        gemm_bt<CDIM, CDIM, 2, 128, 64, 0, 1, 1><<<gP, 256, 0, stream>>>(
            hbuf, wo, bo + l * CDIM, xb, xb);
      ln_kernel<1><<<gLN, 256, 0, stream>>>(xb, ln2g + l * CDIM, ln2b + l * CDIM, hbuf);
      gemm_bt<FFDIM, CDIM, 1, 256, 128><<<gF1, 512, 0, stream>>>(
          hbuf, w1, b1 + l * FFDIM, nullptr, big);
      if (l == DEPTH - 1)
        gemm_bt<CDIM, FFDIM, 2, 128, 64, 0, 1, 0><<<gP, 256, 0, stream>>>(
            big, w2, b2 + l * CDIM, xb, d_out);
      else
        gemm_bt<CDIM, FFDIM, 2, 128, 64, 0, 1, 1><<<gP, 256, 0, stream>>>(
            big, w2, b2 + l * CDIM, xb, xb);
    } else {
      // ---- fallback: f32 residual stream in d_out ----
      const float* xin_l = (l == 0) ? x_in : x;
      ln_kernel<0><<<gLN, 256, 0, stream>>>(xin_l, ln1g + l * CDIM, ln1b + l * CDIM, hbuf);
      gemm_bt<3 * CDIM, CDIM, 0, 256, 128, 1><<<gQKV, 512, 0, stream>>>(
          hbuf, wq, bq, nullptr, big);
      attn_kernel<<<gAT, 256, 0, stream>>>(big, hbuf);
      gemm_bt<CDIM, CDIM, 2, 128, 64><<<gP, 256, 0, stream>>>(
          hbuf, wo, bo + l * CDIM, xin_l, x);
      ln_kernel<0><<<gLN, 256, 0, stream>>>(x, ln2g + l * CDIM, ln2b + l * CDIM, hbuf);
      gemm_bt<FFDIM, CDIM, 1, 256, 128><<<gF1, 512, 0, stream>>>(
          hbuf, w1, b1 + l * FFDIM, nullptr, big);
      gemm_bt<CDIM, FFDIM, 2, 128, 64><<<gP, 256, 0, stream>>>(
          big, w2, b2 + l * CDIM, x, x);
    }
  }
}

// Round 19
// 473.178 us; speedup vs baseline: 1.0637x; 1.0637x over previous
//
#include <hip/hip_runtime.h>

#define DEPTH 4
#define CDIM 512
#define TDIM 1024
#define BDIM 8
#define HDIM 8
#define DHEAD 64
#define FFDIM 2048
#define MROWS (BDIM*TDIM)  // 8192 rows

// softmax scale folded into Wq/bq: 0.125 * log2(e)
#define QK_SCALE_LOG2E 0.18033688f

typedef __attribute__((ext_vector_type(8))) short bf16x8;
typedef __attribute__((ext_vector_type(4))) short s16x4;
typedef __attribute__((ext_vector_type(4))) float f32x4;

__device__ __forceinline__ f32x4 mfma16(bf16x8 a, bf16x8 b, f32x4 c) {
  return __builtin_amdgcn_mfma_f32_16x16x32_bf16(a, b, c, 0, 0, 0);
}

__device__ __forceinline__ unsigned short f2bf(float f) {
  union { float f; unsigned u; } v; v.f = f;
  unsigned r = v.u + 0x7fffu + ((v.u >> 16) & 1u);
  return (unsigned short)(r >> 16);
}

__device__ __forceinline__ float bf2f(unsigned short u) {
  return __uint_as_float((unsigned)u << 16);
}

__device__ __forceinline__ void gload_lds16(const void* g, void* l) {
  __builtin_amdgcn_global_load_lds(
      (const __attribute__((address_space(1))) unsigned int*)g,
      (__attribute__((address_space(3))) unsigned int*)l, 16, 0, 0);
}

__device__ __forceinline__ unsigned lds_addr(const void* p) {
  return (unsigned)(unsigned long long)p;
}

// gelu(x) = x * sigmoid(1.5957691*(x+0.044715x^3)); exp2 form folds log2e
// into the constant: 1.5957691*log2e = 2.3022082. Overflow-safe both ends.
__device__ __forceinline__ float gelu_f(float x) {
  float u = 2.3022082f * (x + 0.044715f * x * x * x);
  return x * __builtin_amdgcn_rcpf(1.0f + __builtin_amdgcn_exp2f(-u));
}

// ---------------- weight transpose + cast: W[K][N] f32 -> Wt[N][K] bf16 ----
// Output rows n < scale_rows are multiplied by scale (Q-column softmax fold).
__global__ __launch_bounds__(256)
void transpose_cast(const float* __restrict__ W, unsigned short* __restrict__ Wt,
                    int K, int N, int scale_rows, float scale) {
  __shared__ float t[32][33];
  const int zl = blockIdx.z;
  W  += (size_t)zl * K * N;
  Wt += (size_t)zl * K * N;
  int n0 = blockIdx.x * 32, k0 = blockIdx.y * 32;
  int tx = threadIdx.x & 31, ty = threadIdx.x >> 5;  // 32 x 8
  for (int i = 0; i < 32; i += 8)
    t[ty + i][tx] = W[(size_t)(k0 + ty + i) * N + n0 + tx];
  __syncthreads();
  for (int i = 0; i < 32; i += 8) {
    float v = t[tx][ty + i];
    if (n0 + ty + i < scale_rows) v *= scale;
    Wt[(size_t)(n0 + ty + i) * K + k0 + tx] = f2bf(v);
  }
}

// ---------------- LayerNorm: x (f32 or bf16) [8192][512] -> h bf16 ---------
template<int BF>
__global__ __launch_bounds__(256)
void ln_kernel(const void* __restrict__ xv, const float* __restrict__ g,
               const float* __restrict__ bta, unsigned short* __restrict__ h) {
  int row  = blockIdx.x * 4 + (threadIdx.x >> 6);
  int lane = threadIdx.x & 63;
  float vv[8];
  if (BF) {
    const unsigned short* xr = (const unsigned short*)xv + (size_t)row * CDIM;
    bf16x8 b0 = *(const bf16x8*)(xr + lane * 8);
    for (int j = 0; j < 8; ++j) vv[j] = bf2f(((const unsigned short*)&b0)[j]);
  } else {
    const float* xr = (const float*)xv + (size_t)row * CDIM;
    float4 v0 = ((const float4*)xr)[lane * 2];
    float4 v1 = ((const float4*)xr)[lane * 2 + 1];
    vv[0] = v0.x; vv[1] = v0.y; vv[2] = v0.z; vv[3] = v0.w;
    vv[4] = v1.x; vv[5] = v1.y; vv[6] = v1.z; vv[7] = v1.w;
  }
  float s = 0.f, sq = 0.f;
  for (int j = 0; j < 8; ++j) { s += vv[j]; sq += vv[j] * vv[j]; }
  for (int m = 1; m < 64; m <<= 1) { s += __shfl_xor(s, m); sq += __shfl_xor(sq, m); }
  float mu  = s * (1.0f / CDIM);
  float var = sq * (1.0f / CDIM) - mu * mu;
  float rs  = rsqrtf(var + 1e-5f);
  int c0 = lane * 8;
  bf16x8 hv;
  for (int j = 0; j < 8; ++j)
    ((short*)&hv)[j] = (short)f2bf((vv[j] - mu) * rs * g[c0 + j] + bta[c0 + j]);
  *(bf16x8*)(h + (size_t)row * CDIM + c0) = hv;
}

// ---------------- GEMM: C[M,N] = A[M,K](bf16) @ Bt[N,K]^T(bf16) + epilogue -
// EPI 0: +bias -> bf16 (trunc).  EPI 1: gelu(+bias) -> bf16 (trunc).
// EPI 2: +bias+resid; RBF: resid is bf16; OBF: output bf16 (f2bf) else f32.
// QSC: scale bias for cols<CDIM (Q-column weight fold).
// BK=64, 8-slot XOR swizzle via pre-swizzled global source.
// Depth-1 / 3-buffer rotation, SINGLE barrier/K-step, ISSUE-BEFORE-WAIT:
//   stage(ks+1) -> vmcnt(LVM) -> barrier -> reads+MFMA.  (depth-2 with
//   stage-after-barrier measured -26 us: issue must overlap the wait.)
// BM=256,BN=128 (QKV/FFN1): 512 thr, 8 waves 4x2, 144KB LDS, 1 block/CU.
// BM=128,BN=64 (proj/FFN2): 256 thr, 4 waves, 72KB LDS, 2 blocks/CU.
template<int N, int K, int EPI, int BM, int BN, int QSC = 0, int RBF = 0, int OBF = 0>
__global__ __launch_bounds__((BM == 256) ? 512 : 256, 2)
void gemm_bt(const unsigned short* __restrict__ A,
             const unsigned short* __restrict__ Bt,
             const float* __restrict__ bias,
             const void* __restrict__ resid,
             void* __restrict__ outp) {
  constexpr int THREADS = (BM == 256) ? 512 : 256;
  constexpr int NWAVE   = THREADS / 64;
  constexpr int WCN     = BN / 64;            // wave columns (2 or 1)
  constexpr int WRN     = NWAVE / WCN;        // wave rows (4)
  constexpr int MI      = BM / WRN / 16;      // acc row-frags per wave (4 or 2)
  constexpr int NK      = K / 64;
  constexpr int LVM     = (BM + BN) * 8 / THREADS;  // = 6 for both variants
  constexpr int NBUF    = 3;
  __shared__ unsigned short As[NBUF][BM * 64];
  __shared__ unsigned short Bs[NBUF][BN * 64];
  const int tid  = threadIdx.x;
  const int wave = tid >> 6, lane = tid & 63;
  const int l16  = lane & 15, lq = lane >> 4;
  const int tm = blockIdx.x, tn = blockIdx.y;
  const int wr = wave / WCN, wc = wave % WCN;

  auto stage = [&](int ks, int bb) {
    for (int it = 0; it < BM * 8 / THREADS; ++it) {   // A: BM rows x 128B
      int idx = it * THREADS + tid;
      int row = idx >> 3;
      int co  = ((idx & 7) ^ (row & 7)) * 8;  // pre-swizzled source slot
      gload_lds16(A + (size_t)(tm * BM + row) * K + ks * 64 + co,
                  &As[bb][(it * THREADS + wave * 64) * 8]);
    }
    for (int it = 0; it < BN * 8 / THREADS; ++it) {   // B: BN rows x 128B
      int idx = it * THREADS + tid;
      int row = idx >> 3;
      int co  = ((idx & 7) ^ (row & 7)) * 8;
      gload_lds16(Bt + (size_t)(tn * BN + row) * K + ks * 64 + co,
                  &Bs[bb][(it * THREADS + wave * 64) * 8]);
    }
  };

  f32x4 acc[MI][4] = {};
  stage(0, 0);
  int cur = 0;
  for (int ks = 0; ks < NK; ++ks) {
    if (ks + 1 < NK) {
      int nb = cur + 1; if (nb == NBUF) nb = 0;
      stage(ks + 1, nb);                           // prefetch stays in flight
      asm volatile("s_waitcnt vmcnt(%c0)" :: "i"(LVM) : "memory");
    } else {
      asm volatile("s_waitcnt vmcnt(0)" ::: "memory");
    }
    asm volatile("s_barrier" ::: "memory");        // the ONLY barrier per step
    bf16x8 af[MI][2], bfr[4][2];
    const char* aBase = (const char*)&As[cur][0];
    const char* bBase = (const char*)&Bs[cur][0];
    const int swz = (l16 & 7);
    #pragma unroll
    for (int i = 0; i < MI; ++i) {
      int row = wr * (MI * 16) + i * 16 + l16;
      #pragma unroll
      for (int t = 0; t < 2; ++t)
        af[i][t] = *(const bf16x8*)(aBase + row * 128 + (((t * 4 + lq) ^ swz) * 16));
    }
    #pragma unroll
    for (int j = 0; j < 4; ++j) {
      int row = wc * 64 + j * 16 + l16;
      #pragma unroll
      for (int t = 0; t < 2; ++t)
        bfr[j][t] = *(const bf16x8*)(bBase + row * 128 + (((t * 4 + lq) ^ swz) * 16));
    }
    __builtin_amdgcn_s_setprio(1);
    #pragma unroll
    for (int t = 0; t < 2; ++t)
      #pragma unroll
      for (int i = 0; i < MI; ++i)
        #pragma unroll
        for (int j = 0; j < 4; ++j)
          acc[i][j] = mfma16(af[i][t], bfr[j][t], acc[i][j]);
    __builtin_amdgcn_s_setprio(0);
    ++cur; if (cur == NBUF) cur = 0;               // no trailing barrier
  }
  const int rowbase = tm * BM + wr * (MI * 16);
  const int colbase = tn * BN + wc * 64;
  for (int j = 0; j < 4; ++j) {
    int col = colbase + j * 16 + l16;
    float bv = bias[col];
    if (QSC && col < CDIM) bv *= QK_SCALE_LOG2E;   // Q-column bias fold
    for (int i = 0; i < MI; ++i) {
      for (int r = 0; r < 4; ++r) {
        int row = rowbase + i * 16 + lq * 4 + r;
        float v = acc[i][j][r] + bv;
        if (EPI == 1) v = gelu_f(v);
        if (EPI == 2) {
          size_t off = (size_t)row * N + col;
          float rv = RBF ? bf2f(((const unsigned short*)resid)[off])
                         : ((const float*)resid)[off];
          float sv = v + rv;
          if (OBF) ((unsigned short*)outp)[off] = f2bf(sv);  // RNE: x-walk safe
          else     ((float*)outp)[off] = sv;
        } else {
          // bf16 truncation store -> global_store_short_d16_hi (no round ops)
          ((unsigned short*)outp)[(size_t)row * N + col] =
              (unsigned short)(__float_as_uint(v) >> 16);
        }
      }
    }
  }
}

// ---------------- flash attention: qkv bf16 [8192][1536] -> o bf16 [8192][512]
// (round-16 proven config) QBLK=128, 4 waves. Q-columns pre-scaled by
// 0.125*log2e -> p = exp2(s). K staged to LDS (byte-swizzled), V tr-subtiled
// with 528-elem chunk stride (conflict-free tr-reads). d16_hi P-store.
// 3-buffer K/V rotation -> single barrier/tile. blockIdx&7 = batch (XCD-pin).
__global__ __launch_bounds__(256, 2)
void attn_kernel(const unsigned short* __restrict__ qkv,
                 unsigned short* __restrict__ o) {
  __shared__ unsigned short Ks[3][64 * 64];
  __shared__ unsigned short Vs[3][8 * 528];   // 8 chunks x 528 (16 pad elems)
  __shared__ unsigned short Ps[128 * 72];
  const int tid  = threadIdx.x;
  const int wave = tid >> 6, lane = tid & 63;
  const int l16  = lane & 15, lq = lane >> 4;
  const int bid  = blockIdx.x;
  const int b    = bid & 7;                   // XCD-pinned batch
  const int h    = (bid >> 3) & 7;
  const int qt   = bid >> 6;                  // 0..7 (128-row q tiles)
  const size_t rowbase = (size_t)b * TDIM;
  const int swzA = (l16 & 7) << 4;

  // ---- Q in registers: A-frag rows = qt*128 + mi*64 + wave*16 + l16 ----
  bf16x8 aq[2][2];
  #pragma unroll
  for (int mi = 0; mi < 2; ++mi) {
    const unsigned short* qr =
        qkv + (rowbase + qt * 128 + mi * 64 + wave * 16 + l16) * (3 * CDIM) + h * DHEAD;
    aq[mi][0] = *(const bf16x8*)(qr + lq * 8);
    aq[mi][1] = *(const bf16x8*)(qr + 32 + lq * 8);
  }

  auto stageKV = [&](int kvt, int bb) {
    for (int it = 0; it < 2; ++it) {
      int i  = it * 256 + tid;
      int r  = i >> 3;
      int cb = ((i & 7) << 4) ^ ((r & 7) << 4);
      gload_lds16(qkv + (rowbase + kvt * 64 + r) * (3 * CDIM) + CDIM + h * DHEAD + (cb >> 1),
                  &Ks[bb][(it * 256 + wave * 64) * 8]);
      int c  = it * 4 + wave;                       // chunk 0..7 (512 elems)
      int k2 = (c * 2 + (lane >> 5)) * 4 + ((lane >> 1) & 3);
      int d0 = ((lane >> 3) & 3) * 16 + (lane & 1) * 8;
      gload_lds16(qkv + (rowbase + kvt * 64 + k2) * (3 * CDIM) + 2 * CDIM + h * DHEAD + d0,
                  &Vs[bb][c * 528]);                // padded chunk stride
    }
  };

  stageKV(0, 0);                                    // 4 loads in flight

  f32x4 ofr[2][4] = {};
  float lsum[2][4] = {};
  const unsigned psbase =
      lds_addr(Ps) + ((unsigned)(wave * 16 + lq * 4) * 72 + l16) * 2;

  int cur = 0;
  for (int kv = 0; kv < TDIM / 64; ++kv) {
    if (kv < TDIM / 64 - 1) {
      int nb = cur + 1; if (nb == 3) nb = 0;
      stageKV(kv + 1, nb);                          // prefetch next tile
      asm volatile("s_waitcnt vmcnt(4)" ::: "memory");  // cur tile landed
    } else {
      asm volatile("s_waitcnt vmcnt(0)" ::: "memory");
    }
    asm volatile("s_barrier" ::: "memory");         // the ONLY barrier per tile

    // ---- S = Q K^T (Q pre-scaled by 0.125*log2e) ----
    f32x4 s[2][4] = {};
    __builtin_amdgcn_s_setprio(1);
    #pragma unroll
    for (int kk = 0; kk < 2; ++kk) {
      bf16x8 bk[4];
      #pragma unroll
      for (int n = 0; n < 4; ++n)
        bk[n] = *(const bf16x8*)((const char*)&Ks[cur][0] +
                  (((n * 16 + l16) * 128 + (kk * 32 + lq * 8) * 2) ^ swzA));
      #pragma unroll
      for (int mi = 0; mi < 2; ++mi)
        #pragma unroll
        for (int n = 0; n < 4; ++n)
          s[mi][n] = mfma16(aq[mi][kk], bk[n], s[mi][n]);
    }
    __builtin_amdgcn_s_setprio(0);

    // ---- issue 16 V tr-reads; exp VALU hides their latency ----
    s16x4 tr[8][2];
    {
      unsigned va = lds_addr(&Vs[cur][0]) + lq * 1056 + l16 * 8;
      #pragma unroll
      for (int kk = 0; kk < 2; ++kk)
        #pragma unroll
        for (int n = 0; n < 4; ++n) {
          asm volatile("ds_read_b64_tr_b16 %0, %1 offset:%c2"
                       : "=v"(tr[kk * 4 + n][0]) : "v"(va), "i"(kk * 4224 + n * 128));
          asm volatile("ds_read_b64_tr_b16 %0, %1 offset:%c2"
                       : "=v"(tr[kk * 4 + n][1]) : "v"(va), "i"(kk * 4224 + n * 128 + 512));
        }
    }

    // ---- p = exp2(s) (scale pre-folded); d16_hi bf16 store (zero VALU) ----
    #pragma unroll
    for (int mi = 0; mi < 2; ++mi)
      #pragma unroll
      for (int n = 0; n < 4; ++n)
        #pragma unroll
        for (int r = 0; r < 4; ++r) {
          float p = __builtin_amdgcn_exp2f(s[mi][n][r]);
          lsum[mi][r] += p;
          asm volatile("ds_write_b16_d16_hi %0, %1 offset:%c2"
                       :: "v"(psbase), "v"(p),
                          "i"(mi * 9216 + r * 144 + n * 32) : "memory");
        }

    asm volatile("s_waitcnt lgkmcnt(0)" ::: "memory");
    __builtin_amdgcn_sched_barrier(0);

    // ---- O += P @ V ----
    __builtin_amdgcn_s_setprio(1);
    #pragma unroll
    for (int kk = 0; kk < 2; ++kk) {
      bf16x8 ap[2];
      #pragma unroll
      for (int mi = 0; mi < 2; ++mi)
        ap[mi] = *(const bf16x8*)&Ps[(mi * 64 + wave * 16 + l16) * 72 + kk * 32 + lq * 8];
      #pragma unroll
      for (int n = 0; n < 4; ++n) {
        bf16x8 bv = __builtin_shufflevector(tr[kk * 4 + n][0], tr[kk * 4 + n][1],
                                            0, 1, 2, 3, 4, 5, 6, 7);
        #pragma unroll
        for (int mi = 0; mi < 2; ++mi)
          ofr[mi][n] = mfma16(ap[mi], bv, ofr[mi][n]);
      }
    }
    __builtin_amdgcn_s_setprio(0);

    ++cur; if (cur == 3) cur = 0;                   // no trailing barrier
  }

  // ---- deferred denominator reduce (once) + output ----
  for (int msk = 1; msk < 16; msk <<= 1)
    #pragma unroll
    for (int mi = 0; mi < 2; ++mi)
      #pragma unroll
      for (int r = 0; r < 4; ++r) lsum[mi][r] += __shfl_xor(lsum[mi][r], msk);
  for (int mi = 0; mi < 2; ++mi)
    for (int n = 0; n < 4; ++n)
      for (int r = 0; r < 4; ++r) {
        size_t row = rowbase + qt * 128 + mi * 64 + wave * 16 + lq * 4 + r;
        o[row * CDIM + h * DHEAD + n * 16 + l16] = f2bf(ofr[mi][n][r] / lsum[mi][r]);
      }
}

// ---------------------------------------------------------------------------
extern "C" void kernel_launch(void* const* d_in, const int* in_sizes, int n_in,
                              void* d_out, int out_size, void* d_ws, size_t ws_size,
                              hipStream_t stream) {
  (void)in_sizes; (void)n_in; (void)out_size;
  const float* x_in = (const float*)d_in[0];
  const float* Wqkv = (const float*)d_in[1];
  const float* bqkv = (const float*)d_in[2];
  const float* Wo   = (const float*)d_in[3];
  const float* bo   = (const float*)d_in[4];
  const float* W1   = (const float*)d_in[5];
  const float* b1   = (const float*)d_in[6];
  const float* W2   = (const float*)d_in[7];
  const float* b2   = (const float*)d_in[8];
  const float* ln1g = (const float*)d_in[9];
  const float* ln1b = (const float*)d_in[10];
  const float* ln2g = (const float*)d_in[11];
  const float* ln2b = (const float*)d_in[12];

  float* x = (float*)d_out;  // f32 residual stream (fallback path)
  unsigned short* hbuf  = (unsigned short*)d_ws;              // 8 MB  (h / o, bf16)
  unsigned short* big   = hbuf  + (size_t)MROWS * CDIM;       // 32 MB (qkv / ff, bf16)
  unsigned short* wqkvT = big   + (size_t)MROWS * FFDIM;      // weights bf16, transposed
  unsigned short* woT   = wqkvT + (size_t)DEPTH * 3 * CDIM * CDIM;
  unsigned short* w1T   = woT   + (size_t)DEPTH * CDIM * CDIM;
  unsigned short* w2T   = w1T   + (size_t)DEPTH * FFDIM * CDIM;
  unsigned short* xb    = w2T   + (size_t)DEPTH * CDIM * FFDIM;  // bf16 x, 8 MB
  const bool useBf16X = ws_size >= (size_t)72 * 1024 * 1024;

  transpose_cast<<<dim3(3 * CDIM / 32, CDIM / 32, DEPTH), 256, 0, stream>>>(
      Wqkv, wqkvT, CDIM, 3 * CDIM, CDIM, QK_SCALE_LOG2E);  // scale Q-columns
  transpose_cast<<<dim3(CDIM / 32, CDIM / 32, DEPTH), 256, 0, stream>>>(
      Wo, woT, CDIM, CDIM, 0, 1.0f);
  transpose_cast<<<dim3(FFDIM / 32, CDIM / 32, DEPTH), 256, 0, stream>>>(
      W1, w1T, CDIM, FFDIM, 0, 1.0f);
  transpose_cast<<<dim3(CDIM / 32, FFDIM / 32, DEPTH), 256, 0, stream>>>(
      W2, w2T, FFDIM, CDIM, 0, 1.0f);

  const dim3 gQKV(MROWS / 256, 3 * CDIM / 128), gP(MROWS / 128, CDIM / 64);
  const dim3 gF1(MROWS / 256, FFDIM / 128), gLN(MROWS / 4);
  const dim3 gAT(BDIM * HDIM * TDIM / 128);

  for (int l = 0; l < DEPTH; ++l) {
    const float* bq = bqkv + l * 3 * CDIM;
    const unsigned short* wq = wqkvT + (size_t)l * 3 * CDIM * CDIM;
    const unsigned short* wo = woT + (size_t)l * CDIM * CDIM;
    const unsigned short* w1 = w1T + (size_t)l * FFDIM * CDIM;
    const unsigned short* w2 = w2T + (size_t)l * CDIM * FFDIM;
    if (useBf16X) {
      // ---- bf16 residual stream in xb; final FFN2 writes f32 d_out ----
      if (l == 0)
        ln_kernel<0><<<gLN, 256, 0, stream>>>(x_in, ln1g, ln1b, hbuf);
      else
        ln_kernel<1><<<gLN, 256, 0, stream>>>(xb, ln1g + l * CDIM, ln1b + l * CDIM, hbuf);
      gemm_bt<3 * CDIM, CDIM, 0, 256, 128, 1><<<gQKV, 512, 0, stream>>>(
          hbuf, wq, bq, nullptr, big);
      attn_kernel<<<gAT, 256, 0, stream>>>(big, hbuf);
      if (l == 0)
        gemm_bt<CDIM, CDIM, 2, 128, 64, 0, 0, 1><<<gP, 256, 0, stream>>>(
            hbuf, wo, bo + l * CDIM, x_in, xb);
      else
        gemm_bt<CDIM, CDIM, 2, 128, 64, 0, 1, 1><<<gP, 256, 0, stream>>>(
            hbuf, wo, bo + l * CDIM, xb, xb);
      ln_kernel<1><<<gLN, 256, 0, stream>>>(xb, ln2g + l * CDIM, ln2b + l * CDIM, hbuf);
      gemm_bt<FFDIM, CDIM, 1, 256, 128><<<gF1, 512, 0, stream>>>(
          hbuf, w1, b1 + l * FFDIM, nullptr, big);
      if (l == DEPTH - 1)
        gemm_bt<CDIM, FFDIM, 2, 128, 64, 0, 1, 0><<<gP, 256, 0, stream>>>(
            big, w2, b2 + l * CDIM, xb, d_out);
      else
        gemm_bt<CDIM, FFDIM, 2, 128, 64, 0, 1, 1><<<gP, 256, 0, stream>>>(
            big, w2, b2 + l * CDIM, xb, xb);
    } else {
      // ---- fallback: f32 residual stream in d_out ----
      const float* xin_l = (l == 0) ? x_in : x;
      ln_kernel<0><<<gLN, 256, 0, stream>>>(xin_l, ln1g + l * CDIM, ln1b + l * CDIM, hbuf);
      gemm_bt<3 * CDIM, CDIM, 0, 256, 128, 1><<<gQKV, 512, 0, stream>>>(
          hbuf, wq, bq, nullptr, big);
      attn_kernel<<<gAT, 256, 0, stream>>>(big, hbuf);
      gemm_bt<CDIM, CDIM, 2, 128, 64><<<gP, 256, 0, stream>>>(
          hbuf, wo, bo + l * CDIM, xin_l, x);
      ln_kernel<0><<<gLN, 256, 0, stream>>>(x, ln2g + l * CDIM, ln2b + l * CDIM, hbuf);
      gemm_bt<FFDIM, CDIM, 1, 256, 128><<<gF1, 512, 0, stream>>>(
          hbuf, w1, b1 + l * FFDIM, nullptr, big);
      gemm_bt<CDIM, FFDIM, 2, 128, 64><<<gP, 256, 0, stream>>>(
          big, w2, b2 + l * CDIM, x, x);
    }
  }
}